// Round 8
// baseline (326.877 us; speedup 1.0000x reference)
//
#include <hip/hip_runtime.h>

#define B_ 16
#define N_ 128
#define CI_ 64
#define CO_ 128
#define T_ 256
#define K_ 9

typedef __attribute__((ext_vector_type(8))) __bf16 bf16x8;
typedef __attribute__((ext_vector_type(4))) float f32x4;
typedef __attribute__((ext_vector_type(8))) unsigned short ushort8;

__device__ __forceinline__ unsigned short tobf(float f) {
  return __builtin_bit_cast(unsigned short, (__bf16)f);
}
// XOR swizzle: physical 8-ushort slot within a row (involution)
__device__ __forceinline__ int swzs(int row, int col0) {
  return ((col0 >> 3) ^ (row & 7)) << 3;
}
__device__ __forceinline__ int swz(int row, int col) {
  return (((col >> 3) ^ (row & 7)) << 3) | (col & 7);
}
// frag-packed global load: p is per-thread base (already + lane*8), idx in ushort8 units
#define FRAG(p, idx) (*(const bf16x8*)((p) + (size_t)(idx) * 8))

// async global->LDS 16B: per-lane global src, wave-uniform LDS base (+lane*16B)
__device__ __forceinline__ void gload16(const void* g, void* l) {
  __builtin_amdgcn_global_load_lds(
      (const __attribute__((address_space(1))) void*)g,
      (__attribute__((address_space(3))) void*)l, 16, 0, 0);
}

// ---------------------------------------------------------------------------
// Prep: fragment-major bf16 weight packs. Frag slot = 64 lanes x ushort8.
// ---------------------------------------------------------------------------
__global__ __launch_bounds__(256) void k_prep(
    const float* __restrict__ w1, const float* __restrict__ w2,
    const float* __restrict__ wsp, const float* __restrict__ wr,
    const float* __restrict__ adj,
    unsigned short* __restrict__ w1f, unsigned short* __restrict__ w2f,
    unsigned short* __restrict__ wrf, unsigned short* __restrict__ wspf,
    unsigned short* __restrict__ adjf) {
  int idx = blockIdx.x * 256 + threadIdx.x;
  int stride = gridDim.x * 256;
  for (int i = idx; i < 73728; i += stride) {
    int e = i & 7, lane = (i >> 3) & 63, ni = (i >> 9) & 3, cg = (i >> 11) & 1;
    int kb = (i >> 12) & 1, k = i >> 13;
    int co = cg * 64 + ni * 16 + (lane & 15), ci = kb * 32 + (lane >> 4) * 8 + e;
    w1f[i] = tobf(w1[(co * 64 + ci) * 9 + k]);
  }
  for (int i = idx; i < 147456; i += stride) {
    int e = i & 7, lane = (i >> 3) & 63, ni = (i >> 9) & 3, cg = (i >> 11) & 1;
    int kb = (i >> 12) & 3, k = i >> 14;
    int co = cg * 64 + ni * 16 + (lane & 15), c = kb * 32 + (lane >> 4) * 8 + e;
    w2f[i] = tobf(w2[(co * 128 + c) * 9 + k]);
  }
  for (int i = idx; i < 8192; i += stride) {
    int e = i & 7, lane = (i >> 3) & 63, ni = (i >> 9) & 3, cg = (i >> 11) & 1;
    int kb = i >> 12;
    int co = cg * 64 + ni * 16 + (lane & 15), ci = kb * 32 + (lane >> 4) * 8 + e;
    wrf[i] = tobf(wr[co * 64 + ci]);
  }
  for (int i = idx; i < 16384; i += stride) {
    int e = i & 7, lane = (i >> 3) & 63, mi = (i >> 9) & 3, og = (i >> 11) & 1;
    int kb = i >> 12;
    int o = og * 64 + mi * 16 + (lane & 15), c = kb * 32 + (lane >> 4) * 8 + e;
    wspf[i] = tobf(wsp[c * 128 + o]);
  }
  for (int i = idx; i < 262144; i += stride) {
    int e = i & 7, lane = (i >> 3) & 63, ni = (i >> 9) & 1, ng = (i >> 10) & 3;
    int kb = (i >> 12) & 3, b = i >> 14;
    int nn = ng * 32 + ni * 16 + (lane & 15), m = kb * 32 + (lane >> 4) * 8 + e;
    adjf[i] = tobf(adj[(b * 128 + nn) * 128 + m]);
  }
}

// ---------------------------------------------------------------------------
// conv1 + bias + relu -> h1 (b,t,n,co) bf16; emits xT (b,n,t,ci) byproduct.
// Block = bn, full T: 256 thr = 4 waves by t, wave = 64t x 128co (ni=8).
// Halved LDS reads/iter vs 128tx64co; B-frags (all co) streamed from L2.
// ---------------------------------------------------------------------------
__global__ __launch_bounds__(256, 2) void k_conv1(
    const float* __restrict__ x, const unsigned short* __restrict__ w1f,
    const float* __restrict__ b1, unsigned short* __restrict__ h1,
    unsigned short* __restrict__ xT) {
  __shared__ alignas(16) char smem[33792];
  unsigned short* xs = (unsigned short*)smem;   // [264][64], row r = t+4
  unsigned short* ot = (unsigned short*)smem;   // reuse: [128][128] out chunk

  int tid = threadIdx.x, bn = blockIdx.x;
  const float* xb = x + (size_t)bn * CI_ * T_;
#pragma unroll
  for (int it = 0; it < 16; ++it) {
    int idx = it * 256 + tid;
    int ci = idx >> 6, ch = idx & 63;
    f32x4 v = __builtin_nontemporal_load((const f32x4*)&xb[ci * 256 + ch * 4]);
    int r = 4 + ch * 4;
    xs[(r + 0) * 64 + swz(r + 0, ci)] = tobf(v[0]);
    xs[(r + 1) * 64 + swz(r + 1, ci)] = tobf(v[1]);
    xs[(r + 2) * 64 + swz(r + 2, ci)] = tobf(v[2]);
    xs[(r + 3) * 64 + swz(r + 3, ci)] = tobf(v[3]);
  }
  for (int i = tid; i < 512; i += 256) {
    int r8 = i >> 6, ci = i & 63;
    int r = (r8 < 4) ? r8 : 256 + r8;
    xs[r * 64 + swz(r, ci)] = 0;
  }

  int lane = tid & 63, wid = tid >> 6;
  int lrow = lane & 15, lk8 = (lane >> 4) * 8, lq = lane >> 4;
  int trow0 = wid * 64;
  const unsigned short* wp = w1f + (size_t)lane * 8;

  f32x4 acc[4][8];
#pragma unroll
  for (int ni = 0; ni < 8; ++ni) {
    float bv = b1[(ni >> 2) * 64 + (ni & 3) * 16 + lrow];
    f32x4 ini = {bv, bv, bv, bv};
#pragma unroll
    for (int mi = 0; mi < 4; ++mi) acc[mi][ni] = ini;
  }
  __syncthreads();

  // emit xT tile from LDS: un-swizzle -> linear global
  {
    unsigned short* xo = xT + (size_t)bn * T_ * 64;
    for (int i = tid; i < 2048; i += 256) {
      int tl = i >> 3, s = i & 7;
      int r = tl + 4;
      *(ushort8*)&xo[tl * 64 + s * 8] =
          *(const ushort8*)&xs[r * 64 + ((s ^ (r & 7)) << 3)];
    }
  }

  bf16x8 bA[8], bB[8];
#pragma unroll
  for (int ni = 0; ni < 8; ++ni) bA[ni] = FRAG(wp, ni * 64);
#pragma unroll 1
  for (int it = 0; it < 18; it += 2) {
#pragma unroll
    for (int ni = 0; ni < 8; ++ni) bB[ni] = FRAG(wp, 512 + ni * 64);
    {
      int k = it >> 1, col0 = lk8;
      bf16x8 a[4];
#pragma unroll
      for (int mi = 0; mi < 4; ++mi) {
        int r = trow0 + mi * 16 + lrow + k;
        a[mi] = *(const bf16x8*)&xs[r * 64 + swzs(r, col0)];
      }
#pragma unroll
      for (int mi = 0; mi < 4; ++mi)
#pragma unroll
        for (int ni = 0; ni < 8; ++ni)
          acc[mi][ni] = __builtin_amdgcn_mfma_f32_16x16x32_bf16(
              a[mi], bA[ni], acc[mi][ni], 0, 0, 0);
    }
    if (it + 2 < 18) {
#pragma unroll
      for (int ni = 0; ni < 8; ++ni) bA[ni] = FRAG(wp, 1024 + ni * 64);
    }
    {
      int k = it >> 1, col0 = 32 + lk8;
      bf16x8 a[4];
#pragma unroll
      for (int mi = 0; mi < 4; ++mi) {
        int r = trow0 + mi * 16 + lrow + k;
        a[mi] = *(const bf16x8*)&xs[r * 64 + swzs(r, col0)];
      }
#pragma unroll
      for (int mi = 0; mi < 4; ++mi)
#pragma unroll
        for (int ni = 0; ni < 8; ++ni)
          acc[mi][ni] = __builtin_amdgcn_mfma_f32_16x16x32_bf16(
              a[mi], bB[ni], acc[mi][ni], 0, 0, 0);
    }
    wp += 8192;
  }
  __syncthreads();

  // epilogue: relu -> swizzled bf16 chunk [128t][128co] -> coalesced global
  int b = bn >> 7, n = bn & 127;
  for (int ch = 0; ch < 2; ++ch) {
    if ((trow0 >> 7) == ch) {
#pragma unroll
      for (int mi = 0; mi < 4; ++mi)
#pragma unroll
        for (int ni = 0; ni < 8; ++ni) {
          int col = (ni >> 2) * 64 + (ni & 3) * 16 + lrow;
#pragma unroll
          for (int r = 0; r < 4; ++r) {
            int row = (trow0 & 127) + mi * 16 + lq * 4 + r;
            float v = acc[mi][ni][r];
            v = v > 0.f ? v : 0.f;
            ot[row * 128 + swz(row, col)] = tobf(v);
          }
        }
    }
    __syncthreads();
    for (int i = tid; i < 128 * 16; i += 256) {
      int tl = i >> 4, s = i & 15;
      int t = ch * 128 + tl;
      int ls = s ^ (tl & 7);
      size_t gb = ((size_t)((b * T_ + t) * N_ + n)) << 7;
      *(ushort8*)&h1[gb + ls * 8] = *(const ushort8*)&ot[tl * 128 + s * 8];
    }
    __syncthreads();
  }
}

// ---------------------------------------------------------------------------
// fused spatial: per (b,t): S = H@Wsp ; H2 = relu(adj@S + bsp). In-place h1.
// 512 thr = 8 waves (2 og x 4 ng). h1t staged via global_load_lds with
// source-preswizzle; wsp/adj A-frags streamed from L2 frag-packed.
// ---------------------------------------------------------------------------
__global__ __launch_bounds__(512, 4) void k_spatial(
    unsigned short* __restrict__ h1, const unsigned short* __restrict__ adjf,
    const unsigned short* __restrict__ wspf, const float* __restrict__ bsp) {
  __shared__ alignas(16) char smem[65536];
  unsigned short* h1t = (unsigned short*)smem;   // [n][c]
  unsigned short* stt = h1t + 16384;             // S^T [o][m]
  unsigned short* ot = h1t;                      // reuse: [n][o]

  int tid = threadIdx.x, blk = blockIdx.x;
  int b = blk >> 8;
  unsigned short* h1g = h1 + ((size_t)blk << 14);
#pragma unroll
  for (int it = 0; it < 4; ++it) {
    int i = it * 512 + tid;
    int n = i >> 4, s = i & 15;
    gload16(h1g + n * 128 + ((s ^ (n & 7)) << 3), h1t + ((i & ~63) << 3));
  }
  int lane = tid & 63, wid = tid >> 6;
  int lrow = lane & 15, lk8 = (lane >> 4) * 8, lq = lane >> 4;
  int og = wid >> 2, ng = wid & 3;
  const unsigned short* sp = wspf + (size_t)(og * 256 + lane) * 8;
  const unsigned short* ap = adjf + ((size_t)b * 2048 + ng * 128 + lane) * 8;

  float bspv[4];
#pragma unroll
  for (int oi = 0; oi < 4; ++oi) bspv[oi] = bsp[og * 64 + oi * 16 + lrow];
  __syncthreads();

  // GEMM1: D[o][n] = sum_c wspT[o][c] * h1t[n][c]
  f32x4 acc1[4][2];
#pragma unroll
  for (int mi = 0; mi < 4; ++mi)
#pragma unroll
    for (int ni = 0; ni < 2; ++ni) acc1[mi][ni] = (f32x4){0.f, 0.f, 0.f, 0.f};
#pragma unroll
  for (int kb = 0; kb < 4; ++kb) {
    int col0 = kb * 32 + lk8;
    bf16x8 aw[4];
#pragma unroll
    for (int mi = 0; mi < 4; ++mi) aw[mi] = FRAG(sp, kb * 512 + mi * 64);
#pragma unroll
    for (int ni = 0; ni < 2; ++ni) {
      int rn = ng * 32 + ni * 16 + lrow;
      bf16x8 bh = *(const bf16x8*)&h1t[rn * 128 + swzs(rn, col0)];
#pragma unroll
      for (int mi = 0; mi < 4; ++mi)
        acc1[mi][ni] = __builtin_amdgcn_mfma_f32_16x16x32_bf16(
            aw[mi], bh, acc1[mi][ni], 0, 0, 0);
    }
  }
#pragma unroll
  for (int mi = 0; mi < 4; ++mi)
#pragma unroll
    for (int ni = 0; ni < 2; ++ni) {
      int ncol = ng * 32 + ni * 16 + lrow;
#pragma unroll
      for (int r = 0; r < 4; ++r) {
        int o = og * 64 + mi * 16 + lq * 4 + r;
        stt[o * 128 + swz(o, ncol)] = tobf(acc1[mi][ni][r]);
      }
    }
  __syncthreads();

  // GEMM2: D[n][o] = sum_m adj[n][m] * S^T[o][m]  (+bias, relu)
  f32x4 acc2[2][4];
#pragma unroll
  for (int oi = 0; oi < 4; ++oi) {
    f32x4 ini = {bspv[oi], bspv[oi], bspv[oi], bspv[oi]};
#pragma unroll
    for (int ni = 0; ni < 2; ++ni) acc2[ni][oi] = ini;
  }
#pragma unroll
  for (int kb = 0; kb < 4; ++kb) {
    int col0 = kb * 32 + lk8;
    bf16x8 aa[2];
#pragma unroll
    for (int ni = 0; ni < 2; ++ni) aa[ni] = FRAG(ap, kb * 512 + ni * 64);
#pragma unroll
    for (int oi = 0; oi < 4; ++oi) {
      int ro = og * 64 + oi * 16 + lrow;
      bf16x8 bs = *(const bf16x8*)&stt[ro * 128 + swzs(ro, col0)];
#pragma unroll
      for (int ni = 0; ni < 2; ++ni)
        acc2[ni][oi] = __builtin_amdgcn_mfma_f32_16x16x32_bf16(
            aa[ni], bs, acc2[ni][oi], 0, 0, 0);
    }
  }
  __syncthreads();
#pragma unroll
  for (int ni = 0; ni < 2; ++ni)
#pragma unroll
    for (int oi = 0; oi < 4; ++oi) {
      int o = og * 64 + oi * 16 + lrow;
#pragma unroll
      for (int r = 0; r < 4; ++r) {
        int nrow = ng * 32 + ni * 16 + lq * 4 + r;
        float v = acc2[ni][oi][r];
        v = v > 0.f ? v : 0.f;
        ot[nrow * 128 + swz(nrow, o)] = tobf(v);
      }
    }
  __syncthreads();
  for (int i = tid; i < 2048; i += 512) {
    int n = i >> 4, s = i & 15;
    int ls = s ^ (n & 7);
    *(ushort8*)&h1g[n * 128 + ls * 8] = *(const ushort8*)&ot[n * 128 + s * 8];
  }
}

// ---------------------------------------------------------------------------
// conv2 + bias + residual(1x1) + bias -> out (b,n,co,t) f32.
// Block = bn, full T: 256 thr = 4 waves by t, wave = 64t x 128co (ni=8).
// h2t [264][128] staged via gload_lds; B-frags dist-1 register pipeline.
// Epilogue: direct nontemporal f32x4 stores.
// ---------------------------------------------------------------------------
__global__ __launch_bounds__(256, 2) void k_conv2(
    const unsigned short* __restrict__ H2, const unsigned short* __restrict__ xT,
    const unsigned short* __restrict__ w2f, const unsigned short* __restrict__ wrf,
    const float* __restrict__ b2, const float* __restrict__ br,
    float* __restrict__ out) {
  __shared__ alignas(16) char smem[67584];
  unsigned short* h2t = (unsigned short*)smem;   // [264][128], row r = t+4

  int tid = threadIdx.x, bn = blockIdx.x;
  int b = bn >> 7, n = bn & 127;
  ushort8 zv = {0, 0, 0, 0, 0, 0, 0, 0};
  size_t h2base = ((size_t)(b * T_) * N_ + n) << 7;
#pragma unroll
  for (int it = 0; it < 16; ++it) {
    int i = it * 256 + tid;
    int t = i >> 4, s = i & 15;
    gload16(H2 + h2base + (size_t)t * (N_ * CO_) + ((s ^ ((t + 4) & 7)) << 3),
            h2t + 512 + ((i & ~63) << 3));
  }
  if (tid < 128) {
    int rr = tid >> 4, s = tid & 15;
    int r = (rr < 4) ? rr : 256 + rr;
    *(ushort8*)&h2t[r * 128 + s * 8] = zv;
  }

  int lane = tid & 63, wid = tid >> 6;
  int lrow = lane & 15, lk8 = (lane >> 4) * 8, lq = lane >> 4;
  int trow0 = wid * 64;
  const unsigned short* wpc = w2f + (size_t)lane * 8;
  const unsigned short* rp = wrf + (size_t)lane * 8;

  f32x4 acc[4][8];
#pragma unroll
  for (int ni = 0; ni < 8; ++ni) {
    int co = (ni >> 2) * 64 + (ni & 3) * 16 + lrow;
    float bv = b2[co] + br[co];
    f32x4 ini = {bv, bv, bv, bv};
#pragma unroll
    for (int mi = 0; mi < 4; ++mi) acc[mi][ni] = ini;
  }
  bf16x8 bA[8], bB[8];
#pragma unroll
  for (int ni = 0; ni < 8; ++ni) bA[ni] = FRAG(wpc, ni * 64);
  __syncthreads();

#pragma unroll 1
  for (int it = 0; it < 36; it += 2) {
#pragma unroll
    for (int ni = 0; ni < 8; ++ni) bB[ni] = FRAG(wpc, 512 + ni * 64);
    {
      int k = it >> 2, col0 = (it & 3) * 32 + lk8;
      bf16x8 a[4];
#pragma unroll
      for (int mi = 0; mi < 4; ++mi) {
        int r = trow0 + mi * 16 + lrow + k;
        a[mi] = *(const bf16x8*)&h2t[r * 128 + swzs(r, col0)];
      }
#pragma unroll
      for (int mi = 0; mi < 4; ++mi)
#pragma unroll
        for (int ni = 0; ni < 8; ++ni)
          acc[mi][ni] = __builtin_amdgcn_mfma_f32_16x16x32_bf16(
              a[mi], bA[ni], acc[mi][ni], 0, 0, 0);
    }
    if (it + 2 < 36) {
#pragma unroll
      for (int ni = 0; ni < 8; ++ni) bA[ni] = FRAG(wpc, 1024 + ni * 64);
    }
    {
      int it1 = it + 1;
      int k = it1 >> 2, col0 = (it1 & 3) * 32 + lk8;
      bf16x8 a[4];
#pragma unroll
      for (int mi = 0; mi < 4; ++mi) {
        int r = trow0 + mi * 16 + lrow + k;
        a[mi] = *(const bf16x8*)&h2t[r * 128 + swzs(r, col0)];
      }
#pragma unroll
      for (int mi = 0; mi < 4; ++mi)
#pragma unroll
        for (int ni = 0; ni < 8; ++ni)
          acc[mi][ni] = __builtin_amdgcn_mfma_f32_16x16x32_bf16(
              a[mi], bB[ni], acc[mi][ni], 0, 0, 0);
    }
    wpc += 8192;
  }

  // residual 1x1: A rows direct from xT, B from wrf (L2)
  const unsigned short* xg = xT + (size_t)bn * T_ * 64;
#pragma unroll
  for (int kb = 0; kb < 2; ++kb) {
    int c0 = kb * 32 + lk8;
    bf16x8 bfr[8];
#pragma unroll
    for (int ni = 0; ni < 8; ++ni) bfr[ni] = FRAG(rp, kb * 512 + ni * 64);
    bf16x8 a[4];
#pragma unroll
    for (int mi = 0; mi < 4; ++mi)
      a[mi] = *(const bf16x8*)&xg[(trow0 + mi * 16 + lrow) * 64 + c0];
#pragma unroll
    for (int mi = 0; mi < 4; ++mi)
#pragma unroll
      for (int ni = 0; ni < 8; ++ni)
        acc[mi][ni] = __builtin_amdgcn_mfma_f32_16x16x32_bf16(
            a[mi], bfr[ni], acc[mi][ni], 0, 0, 0);
  }

  // epilogue: direct nontemporal stores; lane co = (ni>>2)*64+(ni&3)*16+lrow,
  // t = trow0 + mi*16 + lq*4 + [0..3]
  float* ob = out + (size_t)bn * 128 * 256;
#pragma unroll
  for (int mi = 0; mi < 4; ++mi)
#pragma unroll
    for (int ni = 0; ni < 8; ++ni) {
      int co = (ni >> 2) * 64 + (ni & 3) * 16 + lrow;
      __builtin_nontemporal_store(
          acc[mi][ni],
          (f32x4*)&ob[(size_t)co * 256 + trow0 + mi * 16 + lq * 4]);
    }
}

// ---------------------------------------------------------------------------
extern "C" void kernel_launch(void* const* d_in, const int* in_sizes, int n_in,
                              void* d_out, int out_size, void* d_ws, size_t ws_size,
                              hipStream_t stream) {
  const float* x = (const float*)d_in[0];
  const float* adj = (const float*)d_in[1];
  const float* w_t1 = (const float*)d_in[2];
  const float* b_t1 = (const float*)d_in[3];
  const float* w_sp = (const float*)d_in[4];
  const float* b_sp = (const float*)d_in[5];
  const float* w_t2 = (const float*)d_in[6];
  const float* b_t2 = (const float*)d_in[7];
  const float* w_res = (const float*)d_in[8];
  const float* b_res = (const float*)d_in[9];
  float* out = (float*)d_out;

  unsigned short* wsu = (unsigned short*)d_ws;
  unsigned short* h1 = wsu;                       // 67108864 (h1, then H2 in place)
  unsigned short* xT = h1 + 67108864;             // 33554432
  unsigned short* w1f = xT + 33554432;            // 73728
  unsigned short* w2f = w1f + 73728;              // 147456
  unsigned short* wrf = w2f + 147456;             // 8192
  unsigned short* wspf = wrf + 8192;              // 16384
  unsigned short* adjf = wspf + 16384;            // 262144

  k_prep<<<512, 256, 0, stream>>>(w_t1, w_t2, w_sp, w_res, adj,
                                  w1f, w2f, wrf, wspf, adjf);
  k_conv1<<<B_ * N_, 256, 0, stream>>>(x, w1f, b_t1, h1, xT);
  k_spatial<<<B_ * T_, 512, 0, stream>>>(h1, adjf, wspf, b_sp);
  k_conv2<<<B_ * N_, 256, 0, stream>>>(h1, xT, w2f, wrf, b_t2, b_res, out);
}

// Round 10
// 323.570 us; speedup vs baseline: 1.0102x; 1.0102x over previous
//
#include <hip/hip_runtime.h>

#define B_ 16
#define N_ 128
#define CI_ 64
#define CO_ 128
#define T_ 256
#define K_ 9

typedef __attribute__((ext_vector_type(8))) __bf16 bf16x8;
typedef __attribute__((ext_vector_type(4))) float f32x4;
typedef __attribute__((ext_vector_type(8))) unsigned short ushort8;

__device__ __forceinline__ unsigned short tobf(float f) {
  return __builtin_bit_cast(unsigned short, (__bf16)f);
}
// XOR swizzle: physical 8-ushort slot within a row (involution)
__device__ __forceinline__ int swzs(int row, int col0) {
  return ((col0 >> 3) ^ (row & 7)) << 3;
}
__device__ __forceinline__ int swz(int row, int col) {
  return (((col >> 3) ^ (row & 7)) << 3) | (col & 7);
}
// frag-packed global load: p is per-thread base (already + lane*8), idx in ushort8 units
#define FRAG(p, idx) (*(const bf16x8*)((p) + (size_t)(idx) * 8))

// async global->LDS 16B: per-lane global src, wave-uniform LDS base (+lane*16B)
__device__ __forceinline__ void gload16(const void* g, void* l) {
  __builtin_amdgcn_global_load_lds(
      (const __attribute__((address_space(1))) void*)g,
      (__attribute__((address_space(3))) void*)l, 16, 0, 0);
}

// ---------------------------------------------------------------------------
// Prep: fragment-major bf16 weight packs. Frag slot = 64 lanes x ushort8.
// ---------------------------------------------------------------------------
__global__ __launch_bounds__(256) void k_prep(
    const float* __restrict__ w1, const float* __restrict__ w2,
    const float* __restrict__ wsp, const float* __restrict__ wr,
    const float* __restrict__ adj,
    unsigned short* __restrict__ w1f, unsigned short* __restrict__ w2f,
    unsigned short* __restrict__ wrf, unsigned short* __restrict__ wspf,
    unsigned short* __restrict__ adjf) {
  int idx = blockIdx.x * 256 + threadIdx.x;
  int stride = gridDim.x * 256;
  for (int i = idx; i < 73728; i += stride) {
    int e = i & 7, lane = (i >> 3) & 63, ni = (i >> 9) & 3, cg = (i >> 11) & 1;
    int kb = (i >> 12) & 1, k = i >> 13;
    int co = cg * 64 + ni * 16 + (lane & 15), ci = kb * 32 + (lane >> 4) * 8 + e;
    w1f[i] = tobf(w1[(co * 64 + ci) * 9 + k]);
  }
  for (int i = idx; i < 147456; i += stride) {
    int e = i & 7, lane = (i >> 3) & 63, ni = (i >> 9) & 3, cg = (i >> 11) & 1;
    int kb = (i >> 12) & 3, k = i >> 14;
    int co = cg * 64 + ni * 16 + (lane & 15), c = kb * 32 + (lane >> 4) * 8 + e;
    w2f[i] = tobf(w2[(co * 128 + c) * 9 + k]);
  }
  for (int i = idx; i < 8192; i += stride) {
    int e = i & 7, lane = (i >> 3) & 63, ni = (i >> 9) & 3, cg = (i >> 11) & 1;
    int kb = i >> 12;
    int co = cg * 64 + ni * 16 + (lane & 15), ci = kb * 32 + (lane >> 4) * 8 + e;
    wrf[i] = tobf(wr[co * 64 + ci]);
  }
  for (int i = idx; i < 16384; i += stride) {
    int e = i & 7, lane = (i >> 3) & 63, mi = (i >> 9) & 3, og = (i >> 11) & 1;
    int kb = i >> 12;
    int o = og * 64 + mi * 16 + (lane & 15), c = kb * 32 + (lane >> 4) * 8 + e;
    wspf[i] = tobf(wsp[c * 128 + o]);
  }
  for (int i = idx; i < 262144; i += stride) {
    int e = i & 7, lane = (i >> 3) & 63, ni = (i >> 9) & 1, ng = (i >> 10) & 3;
    int kb = (i >> 12) & 3, b = i >> 14;
    int nn = ng * 32 + ni * 16 + (lane & 15), m = kb * 32 + (lane >> 4) * 8 + e;
    adjf[i] = tobf(adj[(b * 128 + nn) * 128 + m]);
  }
}

// ---------------------------------------------------------------------------
// conv1 + bias + relu -> h1 (b,t,n,co) bf16; emits xT (b,n,t,ci) byproduct.
// Block = bn, full T: 256 thr = 4 waves (2 tg x 2 cg), wave 128t x 64co.
// x read nontemporal (537 MB read-once stream; keep L3 for h1/xT).
// ---------------------------------------------------------------------------
__global__ __launch_bounds__(256, 2) void k_conv1(
    const float* __restrict__ x, const unsigned short* __restrict__ w1f,
    const float* __restrict__ b1, unsigned short* __restrict__ h1,
    unsigned short* __restrict__ xT) {
  __shared__ alignas(16) char smem[33792];
  unsigned short* xs = (unsigned short*)smem;   // [264][64], row r = t+4
  unsigned short* ot = (unsigned short*)smem;   // reuse: [128][128] out chunk

  int tid = threadIdx.x, bn = blockIdx.x;
  const float* xb = x + (size_t)bn * CI_ * T_;
  // main region: t 0..255 -> rows 4..259, transpose f32->bf16
#pragma unroll
  for (int it = 0; it < 16; ++it) {
    int idx = it * 256 + tid;
    int ci = idx >> 6, ch = idx & 63;
    f32x4 v = __builtin_nontemporal_load((const f32x4*)&xb[ci * 256 + ch * 4]);
    int r = 4 + ch * 4;
    xs[(r + 0) * 64 + swz(r + 0, ci)] = tobf(v[0]);
    xs[(r + 1) * 64 + swz(r + 1, ci)] = tobf(v[1]);
    xs[(r + 2) * 64 + swz(r + 2, ci)] = tobf(v[2]);
    xs[(r + 3) * 64 + swz(r + 3, ci)] = tobf(v[3]);
  }
  // halo rows 0-3 / 260-263 are zero
  for (int i = tid; i < 512; i += 256) {
    int r8 = i >> 6, ci = i & 63;
    int r = (r8 < 4) ? r8 : 256 + r8;
    xs[r * 64 + swz(r, ci)] = 0;
  }

  int lane = tid & 63, wid = tid >> 6;
  int lrow = lane & 15, lk8 = (lane >> 4) * 8, lq = lane >> 4;
  int trow0 = (wid >> 1) * 128, cg = wid & 1;
  const unsigned short* wp = w1f + (size_t)(cg * 256 + lane) * 8;

  f32x4 acc[8][4];
#pragma unroll
  for (int ni = 0; ni < 4; ++ni) {
    float bv = b1[cg * 64 + ni * 16 + lrow];
    f32x4 ini = {bv, bv, bv, bv};
#pragma unroll
    for (int mi = 0; mi < 8; ++mi) acc[mi][ni] = ini;
  }
  __syncthreads();

  // emit xT tile from LDS: un-swizzle -> linear global
  {
    unsigned short* xo = xT + (size_t)bn * T_ * 64;
    for (int i = tid; i < 2048; i += 256) {
      int tl = i >> 3, s = i & 7;
      int r = tl + 4;
      *(ushort8*)&xo[tl * 64 + s * 8] =
          *(const ushort8*)&xs[r * 64 + ((s ^ (r & 7)) << 3)];
    }
  }

  bf16x8 bA[4], bB[4];
#pragma unroll
  for (int ni = 0; ni < 4; ++ni) bA[ni] = FRAG(wp, ni * 64);
#pragma unroll 1
  for (int it = 0; it < 18; it += 2) {
#pragma unroll
    for (int ni = 0; ni < 4; ++ni) bB[ni] = FRAG(wp, 512 + ni * 64);
    {
      int k = it >> 1, col0 = lk8;
      bf16x8 a[8];
#pragma unroll
      for (int mi = 0; mi < 8; ++mi) {
        int r = trow0 + mi * 16 + lrow + k;
        a[mi] = *(const bf16x8*)&xs[r * 64 + swzs(r, col0)];
      }
#pragma unroll
      for (int mi = 0; mi < 8; ++mi)
#pragma unroll
        for (int ni = 0; ni < 4; ++ni)
          acc[mi][ni] = __builtin_amdgcn_mfma_f32_16x16x32_bf16(
              a[mi], bA[ni], acc[mi][ni], 0, 0, 0);
    }
    if (it + 2 < 18) {
#pragma unroll
      for (int ni = 0; ni < 4; ++ni) bA[ni] = FRAG(wp, 1024 + ni * 64);
    }
    {
      int k = it >> 1, col0 = 32 + lk8;
      bf16x8 a[8];
#pragma unroll
      for (int mi = 0; mi < 8; ++mi) {
        int r = trow0 + mi * 16 + lrow + k;
        a[mi] = *(const bf16x8*)&xs[r * 64 + swzs(r, col0)];
      }
#pragma unroll
      for (int mi = 0; mi < 8; ++mi)
#pragma unroll
        for (int ni = 0; ni < 4; ++ni)
          acc[mi][ni] = __builtin_amdgcn_mfma_f32_16x16x32_bf16(
              a[mi], bB[ni], acc[mi][ni], 0, 0, 0);
    }
    wp += 8192;
  }
  __syncthreads();

  // epilogue: relu -> swizzled bf16 chunk [128t][128co] -> coalesced global
  int b = bn >> 7, n = bn & 127;
  for (int ch = 0; ch < 2; ++ch) {
    if ((trow0 >> 7) == ch) {
#pragma unroll
      for (int mi = 0; mi < 8; ++mi)
#pragma unroll
        for (int ni = 0; ni < 4; ++ni) {
          int col = cg * 64 + ni * 16 + lrow;
#pragma unroll
          for (int r = 0; r < 4; ++r) {
            int row = mi * 16 + lq * 4 + r;  // local within chunk
            float v = acc[mi][ni][r];
            v = v > 0.f ? v : 0.f;
            ot[row * 128 + swz(row, col)] = tobf(v);
          }
        }
    }
    __syncthreads();
    for (int i = tid; i < 128 * 16; i += 256) {
      int tl = i >> 4, s = i & 15;
      int t = ch * 128 + tl;
      int ls = s ^ (tl & 7);
      size_t gb = ((size_t)((b * T_ + t) * N_ + n)) << 7;
      *(ushort8*)&h1[gb + ls * 8] = *(const ushort8*)&ot[tl * 128 + s * 8];
    }
    __syncthreads();
  }
}

// ---------------------------------------------------------------------------
// fused spatial: per (b,t): S = H@Wsp ; H2 = relu(adj@S + bsp). In-place h1.
// 512 thr = 8 waves (2 og x 4 ng). h1t staged via global_load_lds with
// source-preswizzle; wsp/adj A-frags streamed from L2 frag-packed.
// ---------------------------------------------------------------------------
__global__ __launch_bounds__(512, 4) void k_spatial(
    unsigned short* __restrict__ h1, const unsigned short* __restrict__ adjf,
    const unsigned short* __restrict__ wspf, const float* __restrict__ bsp) {
  __shared__ alignas(16) char smem[65536];
  unsigned short* h1t = (unsigned short*)smem;   // [n][c]
  unsigned short* stt = h1t + 16384;             // S^T [o][m]
  unsigned short* ot = h1t;                      // reuse: [n][o]

  int tid = threadIdx.x, blk = blockIdx.x;
  int b = blk >> 8;
  unsigned short* h1g = h1 + ((size_t)blk << 14);
#pragma unroll
  for (int it = 0; it < 4; ++it) {
    int i = it * 512 + tid;
    int n = i >> 4, s = i & 15;
    gload16(h1g + n * 128 + ((s ^ (n & 7)) << 3), h1t + ((i & ~63) << 3));
  }
  int lane = tid & 63, wid = tid >> 6;
  int lrow = lane & 15, lk8 = (lane >> 4) * 8, lq = lane >> 4;
  int og = wid >> 2, ng = wid & 3;
  const unsigned short* sp = wspf + (size_t)(og * 256 + lane) * 8;
  const unsigned short* ap = adjf + ((size_t)b * 2048 + ng * 128 + lane) * 8;

  float bspv[4];
#pragma unroll
  for (int oi = 0; oi < 4; ++oi) bspv[oi] = bsp[og * 64 + oi * 16 + lrow];
  __syncthreads();

  // GEMM1: D[o][n] = sum_c wspT[o][c] * h1t[n][c]
  f32x4 acc1[4][2];
#pragma unroll
  for (int mi = 0; mi < 4; ++mi)
#pragma unroll
    for (int ni = 0; ni < 2; ++ni) acc1[mi][ni] = (f32x4){0.f, 0.f, 0.f, 0.f};
#pragma unroll
  for (int kb = 0; kb < 4; ++kb) {
    int col0 = kb * 32 + lk8;
    bf16x8 aw[4];
#pragma unroll
    for (int mi = 0; mi < 4; ++mi) aw[mi] = FRAG(sp, kb * 512 + mi * 64);
#pragma unroll
    for (int ni = 0; ni < 2; ++ni) {
      int rn = ng * 32 + ni * 16 + lrow;
      bf16x8 bh = *(const bf16x8*)&h1t[rn * 128 + swzs(rn, col0)];
#pragma unroll
      for (int mi = 0; mi < 4; ++mi)
        acc1[mi][ni] = __builtin_amdgcn_mfma_f32_16x16x32_bf16(
            aw[mi], bh, acc1[mi][ni], 0, 0, 0);
    }
  }
#pragma unroll
  for (int mi = 0; mi < 4; ++mi)
#pragma unroll
    for (int ni = 0; ni < 2; ++ni) {
      int ncol = ng * 32 + ni * 16 + lrow;
#pragma unroll
      for (int r = 0; r < 4; ++r) {
        int o = og * 64 + mi * 16 + lq * 4 + r;
        stt[o * 128 + swz(o, ncol)] = tobf(acc1[mi][ni][r]);
      }
    }
  __syncthreads();

  // GEMM2: D[n][o] = sum_m adj[n][m] * S^T[o][m]  (+bias, relu)
  f32x4 acc2[2][4];
#pragma unroll
  for (int oi = 0; oi < 4; ++oi) {
    f32x4 ini = {bspv[oi], bspv[oi], bspv[oi], bspv[oi]};
#pragma unroll
    for (int ni = 0; ni < 2; ++ni) acc2[ni][oi] = ini;
  }
#pragma unroll
  for (int kb = 0; kb < 4; ++kb) {
    int col0 = kb * 32 + lk8;
    bf16x8 aa[2];
#pragma unroll
    for (int ni = 0; ni < 2; ++ni) aa[ni] = FRAG(ap, kb * 512 + ni * 64);
#pragma unroll
    for (int oi = 0; oi < 4; ++oi) {
      int ro = og * 64 + oi * 16 + lrow;
      bf16x8 bs = *(const bf16x8*)&stt[ro * 128 + swzs(ro, col0)];
#pragma unroll
      for (int ni = 0; ni < 2; ++ni)
        acc2[ni][oi] = __builtin_amdgcn_mfma_f32_16x16x32_bf16(
            aa[ni], bs, acc2[ni][oi], 0, 0, 0);
    }
  }
  __syncthreads();
#pragma unroll
  for (int ni = 0; ni < 2; ++ni)
#pragma unroll
    for (int oi = 0; oi < 4; ++oi) {
      int o = og * 64 + oi * 16 + lrow;
#pragma unroll
      for (int r = 0; r < 4; ++r) {
        int nrow = ng * 32 + ni * 16 + lq * 4 + r;
        float v = acc2[ni][oi][r];
        v = v > 0.f ? v : 0.f;
        ot[nrow * 128 + swz(nrow, o)] = tobf(v);
      }
    }
  __syncthreads();
  for (int i = tid; i < 2048; i += 512) {
    int n = i >> 4, s = i & 15;
    int ls = s ^ (n & 7);
    *(ushort8*)&h1g[n * 128 + ls * 8] = *(const ushort8*)&ot[n * 128 + s * 8];
  }
}

// ---------------------------------------------------------------------------
// conv2 + bias + residual(1x1) + bias -> out (b,n,co,t) f32.
// Block = bn, full T: 256 thr = 4 waves (2 tg x 2 cg), wave 128t x 64co.
// h2t [264][128] staged via gload_lds; B-frags dist-1 register pipeline.
// Epilogue: direct nontemporal f32x4 stores (4 lanes = one 64B cacheline);
// no LDS round-trip, no epilogue barriers, out stream bypasses L2/L3.
// ---------------------------------------------------------------------------
__global__ __launch_bounds__(256, 2) void k_conv2(
    const unsigned short* __restrict__ H2, const unsigned short* __restrict__ xT,
    const unsigned short* __restrict__ w2f, const unsigned short* __restrict__ wrf,
    const float* __restrict__ b2, const float* __restrict__ br,
    float* __restrict__ out) {
  __shared__ alignas(16) char smem[67584];
  unsigned short* h2t = (unsigned short*)smem;   // [264][128], row r = t+4

  int tid = threadIdx.x, bn = blockIdx.x;
  int b = bn >> 7, n = bn & 127;
  ushort8 zv = {0, 0, 0, 0, 0, 0, 0, 0};
  size_t h2base = ((size_t)(b * T_) * N_ + n) << 7;
#pragma unroll
  for (int it = 0; it < 16; ++it) {
    int i = it * 256 + tid;
    int t = i >> 4, s = i & 15;
    gload16(H2 + h2base + (size_t)t * (N_ * CO_) + ((s ^ ((t + 4) & 7)) << 3),
            h2t + 512 + ((i & ~63) << 3));
  }
  if (tid < 128) {
    int rr = tid >> 4, s = tid & 15;
    int r = (rr < 4) ? rr : 256 + rr;
    *(ushort8*)&h2t[r * 128 + s * 8] = zv;
  }

  int lane = tid & 63, wid = tid >> 6;
  int lrow = lane & 15, lk8 = (lane >> 4) * 8, lq = lane >> 4;
  int trow0 = (wid >> 1) * 128, cg = wid & 1;
  const unsigned short* wpc = w2f + (size_t)(cg * 256 + lane) * 8;
  const unsigned short* rp = wrf + (size_t)(cg * 256 + lane) * 8;

  f32x4 acc[8][4];
#pragma unroll
  for (int ni = 0; ni < 4; ++ni) {
    float bv = b2[cg * 64 + ni * 16 + lrow] + br[cg * 64 + ni * 16 + lrow];
    f32x4 ini = {bv, bv, bv, bv};
#pragma unroll
    for (int mi = 0; mi < 8; ++mi) acc[mi][ni] = ini;
  }
  bf16x8 bA[4], bB[4];
#pragma unroll
  for (int ni = 0; ni < 4; ++ni) bA[ni] = FRAG(wpc, ni * 64);
  __syncthreads();

#pragma unroll 1
  for (int it = 0; it < 36; it += 2) {
#pragma unroll
    for (int ni = 0; ni < 4; ++ni) bB[ni] = FRAG(wpc, 512 + ni * 64);
    {
      int k = it >> 2, col0 = (it & 3) * 32 + lk8;
      bf16x8 a[8];
#pragma unroll
      for (int mi = 0; mi < 8; ++mi) {
        int r = trow0 + mi * 16 + lrow + k;
        a[mi] = *(const bf16x8*)&h2t[r * 128 + swzs(r, col0)];
      }
#pragma unroll
      for (int mi = 0; mi < 8; ++mi)
#pragma unroll
        for (int ni = 0; ni < 4; ++ni)
          acc[mi][ni] = __builtin_amdgcn_mfma_f32_16x16x32_bf16(
              a[mi], bA[ni], acc[mi][ni], 0, 0, 0);
    }
    if (it + 2 < 36) {
#pragma unroll
      for (int ni = 0; ni < 4; ++ni) bA[ni] = FRAG(wpc, 1024 + ni * 64);
    }
    {
      int it1 = it + 1;
      int k = it1 >> 2, col0 = (it1 & 3) * 32 + lk8;
      bf16x8 a[8];
#pragma unroll
      for (int mi = 0; mi < 8; ++mi) {
        int r = trow0 + mi * 16 + lrow + k;
        a[mi] = *(const bf16x8*)&h2t[r * 128 + swzs(r, col0)];
      }
#pragma unroll
      for (int mi = 0; mi < 8; ++mi)
#pragma unroll
        for (int ni = 0; ni < 4; ++ni)
          acc[mi][ni] = __builtin_amdgcn_mfma_f32_16x16x32_bf16(
              a[mi], bB[ni], acc[mi][ni], 0, 0, 0);
    }
    wpc += 8192;
  }

  // residual 1x1: A rows direct from xT, B from wrf (L2)
  const unsigned short* xg = xT + (size_t)bn * T_ * 64;
#pragma unroll
  for (int kb = 0; kb < 2; ++kb) {
    int c0 = kb * 32 + lk8;
    bf16x8 bfr[4];
#pragma unroll
    for (int ni = 0; ni < 4; ++ni) bfr[ni] = FRAG(rp, kb * 512 + ni * 64);
    bf16x8 a[8];
#pragma unroll
    for (int mi = 0; mi < 8; ++mi)
      a[mi] = *(const bf16x8*)&xg[(trow0 + mi * 16 + lrow) * 64 + c0];
#pragma unroll
    for (int mi = 0; mi < 8; ++mi)
#pragma unroll
      for (int ni = 0; ni < 4; ++ni)
        acc[mi][ni] = __builtin_amdgcn_mfma_f32_16x16x32_bf16(
            a[mi], bfr[ni], acc[mi][ni], 0, 0, 0);
  }

  // epilogue: direct nontemporal stores; lane holds co = cg*64+ni*16+lrow,
  // t = trow0 + mi*16 + lq*4 + [0..3]  -> 16B aligned f32x4, 64B per 4 lanes
  float* ob = out + ((size_t)bn * 128 + cg * 64) * 256;
#pragma unroll
  for (int mi = 0; mi < 8; ++mi)
#pragma unroll
    for (int ni = 0; ni < 4; ++ni) {
      __builtin_nontemporal_store(
          acc[mi][ni],
          (f32x4*)&ob[(ni * 16 + lrow) * 256 + trow0 + mi * 16 + lq * 4]);
    }
}

// ---------------------------------------------------------------------------
extern "C" void kernel_launch(void* const* d_in, const int* in_sizes, int n_in,
                              void* d_out, int out_size, void* d_ws, size_t ws_size,
                              hipStream_t stream) {
  const float* x = (const float*)d_in[0];
  const float* adj = (const float*)d_in[1];
  const float* w_t1 = (const float*)d_in[2];
  const float* b_t1 = (const float*)d_in[3];
  const float* w_sp = (const float*)d_in[4];
  const float* b_sp = (const float*)d_in[5];
  const float* w_t2 = (const float*)d_in[6];
  const float* b_t2 = (const float*)d_in[7];
  const float* w_res = (const float*)d_in[8];
  const float* b_res = (const float*)d_in[9];
  float* out = (float*)d_out;

  unsigned short* wsu = (unsigned short*)d_ws;
  unsigned short* h1 = wsu;                       // 67108864 (h1, then H2 in place)
  unsigned short* xT = h1 + 67108864;             // 33554432
  unsigned short* w1f = xT + 33554432;            // 73728
  unsigned short* w2f = w1f + 73728;              // 147456
  unsigned short* wrf = w2f + 147456;             // 8192
  unsigned short* wspf = wrf + 8192;              // 16384
  unsigned short* adjf = wspf + 16384;            // 262144

  k_prep<<<512, 256, 0, stream>>>(w_t1, w_t2, w_sp, w_res, adj,
                                  w1f, w2f, wrf, wspf, adjf);
  k_conv1<<<B_ * N_, 256, 0, stream>>>(x, w1f, b_t1, h1, xT);
  k_spatial<<<B_ * T_, 512, 0, stream>>>(h1, adjf, wspf, b_sp);
  k_conv2<<<B_ * N_, 256, 0, stream>>>(h1, xT, w2f, wrf, b_t2, b_res, out);
}